// Round 7
// baseline (145.624 us; speedup 1.0000x reference)
//
#include <hip/hip_runtime.h>
#include <hip/hip_bf16.h>
#include <cstdint>

typedef uint16_t u16;
typedef __attribute__((ext_vector_type(8))) short short8;
typedef __attribute__((ext_vector_type(4))) float f32x4;
typedef __attribute__((ext_vector_type(4))) float fv4;

static constexpr int S = 4096;
static constexpr int D2 = 512;
static constexpr size_t RET_ELEMS = 16384ull * 512ull;
static constexpr float SCALE = 0.04419417382415922f;   // 512^-0.5

__device__ __forceinline__ u16 f2bf(float f) {
  uint32_t u = __float_as_uint(f);
  u += 0x7fffu + ((u >> 16) & 1u);
  return (u16)(u >> 16);
}

__device__ __forceinline__ float bflo(uint32_t u) { return __uint_as_float(u << 16); }
__device__ __forceinline__ float bfhi(uint32_t u) { return __uint_as_float(u & 0xffff0000u); }

// ---------------- f32 -> bf16 cast ----------------
__global__ void cast_f32_bf16(const float* __restrict__ src, u16* __restrict__ dst, int n4) {
  int idx = blockIdx.x * blockDim.x + threadIdx.x;
  if (idx < n4) {
    float4 v = *(const float4*)(src + (size_t)idx * 4);
    ushort4 o;
    o.x = f2bf(v.x); o.y = f2bf(v.y); o.z = f2bf(v.z); o.w = f2bf(v.w);
    *(ushort4*)(dst + (size_t)idx * 4) = o;
  }
}

// ---------------- MbT[e][d] = bf16( SCALE * sum_k Wq[k][d] * Wk[k][e] ) ----
__global__ __launch_bounds__(256) void m_gemm(const float* __restrict__ Wq,
                                              const float* __restrict__ Wk,
                                              u16* __restrict__ MbT) {
  __shared__ float aq[8][32], ak[8][32];
  const int d0 = (blockIdx.x & 15) * 32;
  const int e0 = (blockIdx.x >> 4) * 32;
  const int tx = threadIdx.x & 15, ty = threadIdx.x >> 4;
  float acc[2][2] = {};
  for (int k0 = 0; k0 < 512; k0 += 8) {
    __syncthreads();
    const int r = threadIdx.x >> 5, c = threadIdx.x & 31;
    aq[r][c] = Wq[(size_t)(k0 + r) * 512 + d0 + c];
    ak[r][c] = Wk[(size_t)(k0 + r) * 512 + e0 + c];
    __syncthreads();
    #pragma unroll
    for (int kk = 0; kk < 8; ++kk) {
      const float q0 = aq[kk][2 * ty], q1 = aq[kk][2 * ty + 1];
      const float w0 = ak[kk][2 * tx], w1 = ak[kk][2 * tx + 1];
      acc[0][0] += q0 * w0; acc[0][1] += q0 * w1;
      acc[1][0] += q1 * w0; acc[1][1] += q1 * w1;
    }
  }
  #pragma unroll
  for (int a = 0; a < 2; ++a)
    #pragma unroll
    for (int c = 0; c < 2; ++c)
      MbT[(size_t)(e0 + 2 * tx + c) * 512 + d0 + 2 * ty + a] = f2bf(acc[a][c] * SCALE);
}

// ---------------- Q' = Xb * MbT^T  (bf16 in/out, f32 acc) ----------------
#define BM 128
#define BN 128
#define BK 32
#define LDSP 40

__global__ __launch_bounds__(256) void q_gemm(
    const u16* __restrict__ Xb, const u16* __restrict__ Bt, u16* __restrict__ Qp) {
  __shared__ u16 Xs[BM * LDSP];
  __shared__ u16 Ws[BN * LDSP];
  const int m0 = blockIdx.x * BM;
  const int n0 = blockIdx.y * BN;

  const int t = threadIdx.x;
  const int lane = t & 63, w = t >> 6;
  const int wm = w >> 1, wn = w & 1;
  const int r16 = lane & 15, kg = lane >> 4;
  const int srow = t >> 2, skcol = (t & 3) * 8;

  f32x4 acc[4][4] = {};

  for (int kt = 0; kt < D2; kt += BK) {
    __syncthreads();
    for (int p = 0; p < 2; ++p) {
      int row = srow + p * 64;
      uint4 va = *(const uint4*)(Xb + (size_t)(m0 + row) * D2 + kt + skcol);
      *(uint4*)(Xs + row * LDSP + skcol) = va;
      uint4 vb = *(const uint4*)(Bt + (size_t)(n0 + row) * D2 + kt + skcol);
      *(uint4*)(Ws + row * LDSP + skcol) = vb;
    }
    __syncthreads();
    short8 a[4], b[4];
    for (int f = 0; f < 4; ++f) {
      a[f] = *(const short8*)(Xs + (wm * 64 + f * 16 + r16) * LDSP + kg * 8);
      b[f] = *(const short8*)(Ws + (wn * 64 + f * 16 + r16) * LDSP + kg * 8);
    }
    for (int fm = 0; fm < 4; ++fm)
      for (int fn = 0; fn < 4; ++fn)
        acc[fm][fn] = __builtin_amdgcn_mfma_f32_16x16x32_bf16(a[fm], b[fn], acc[fm][fn], 0, 0, 0);
  }

  for (int fm = 0; fm < 4; ++fm) {
    int grow = m0 + wm * 64 + fm * 16 + kg * 4;
    for (int fn = 0; fn < 4; ++fn) {
      int gcol = n0 + wn * 64 + fn * 16 + r16;
      for (int r = 0; r < 4; ++r)
        Qp[(size_t)(grow + r) * D2 + gcol] = f2bf(acc[fm][fn][r]);
    }
  }
}

// ---------------- fused banded attention, X staged in LDS ----------------
// 256 blocks x 512 threads (8 waves). Block = 64 queries. 3 phases, 2 barriers:
//  P1: all waves stage X band rows [i0-64, i0+64) into swizzled LDS (128 KB).
//  P2: waves dh=0 compute QK^T+softmax, SOLE writers of p_jm[grp];
//      waves dh=1 do all nontemporal zero-stores (overlaps MFMA).
//  P3: all waves: band writes (8 exclusive rows each) + PV (grp x d-half).
// Every output byte written exactly once per call -> deterministic.
__global__ __launch_bounds__(512) void attn_kernel(
    const u16* __restrict__ Qp, const u16* __restrict__ Xb, float* __restrict__ out) {
  __shared__ u16 xs[128 * 512];          // 128 KB, row stride 1024 B, XOR-swizzled
  __shared__ float p_jm[4][80][16];      // [group][window col][query m]

  const int bid = blockIdx.x;
  const int swz = (bid & 7) * 32 + (bid >> 3);   // XCD-bijective
  const int w = threadIdx.x >> 6;
  const int lane = threadIdx.x & 63;
  const int qg = swz * 64;
  const int b = qg >> 12;
  const int i0 = qg & (S - 1);
  const int c15 = lane & 15, g = lane >> 4;
  const int grp = w & 3, dh = w >> 2;
  const int i0g = i0 + grp * 16;
  const int qgg = qg + grp * 16;

  float* aout = out + RET_ELEMS + (size_t)qg * S;
  const fv4 z4 = {0.f, 0.f, 0.f, 0.f};

  // ---- P1: stage X band (clamped at batch start) into swizzled LDS ----
  {
    const u16* xbat = Xb + (((size_t)b) << 12) * D2;
    const int tid = threadIdx.x;
    #pragma unroll
    for (int cch = 0; cch < 16; ++cch) {
      const int idx8 = tid + (cch << 9);          // 16B chunk id, 0..8191
      const int rl = idx8 >> 6;                   // local row 0..127
      const int cb = (idx8 & 63) << 4;            // byte col in row
      int gr = i0 - 64 + rl; gr = gr < 0 ? 0 : gr;
      const uint4 v = *(const uint4*)(xbat + (size_t)gr * D2 + (cb >> 1));
      *(uint4*)((char*)xs + rl * 1024 + (cb ^ ((rl & 7) << 4))) = v;
    }
  }
  __syncthreads();

  // ---- P2 ----
  if (dh == 0) {
    // QK^T for group grp (B-frags from LDS), softmax, publish p_jm[grp]
    const u16* qptr = Qp + (size_t)(qgg + c15) * D2 + g * 8;
    f32x4 sc[5] = {};
    #pragma unroll 1
    for (int s = 0; s < 16; ++s) {
      const short8 qf = *(const short8*)(qptr + s * 32);
      #pragma unroll
      for (int t = 0; t < 5; ++t) {
        const int rl = grp * 16 + 16 * t + c15;   // local band row
        const int cb = ((s << 6) + (g << 4)) ^ ((rl & 7) << 4);
        const short8 kf = *(const short8*)((const char*)xs + rl * 1024 + cb);
        sc[t] = __builtin_amdgcn_mfma_f32_16x16x32_bf16(qf, kf, sc[t], 0, 0, 0);
      }
    }

    // mask (scale folded into M). C layout: col=lane&15, row=4*(lane>>4)+r
    float sv[5][4];
    #pragma unroll
    for (int t = 0; t < 5; ++t)
      #pragma unroll
      for (int r = 0; r < 4; ++r) {
        const int m = 4 * g + r;
        const int rel = 16 * t + c15 - m;
        const int j = i0g - 64 + 16 * t + c15;
        const bool ok = (rel >= 0) && (rel < 64) && (j >= 0);
        sv[t][r] = ok ? sc[t][r] : -INFINITY;
      }

    // softmax per query row (16-lane group reduce)
    float p[5][4];
    #pragma unroll
    for (int r = 0; r < 4; ++r) {
      float mx = sv[0][r];
      #pragma unroll
      for (int t = 1; t < 5; ++t) mx = fmaxf(mx, sv[t][r]);
      #pragma unroll
      for (int off = 8; off; off >>= 1) mx = fmaxf(mx, __shfl_xor(mx, off));
      float e[5], sum = 0.f;
      #pragma unroll
      for (int t = 0; t < 5; ++t) {
        e[t] = (sv[t][r] == -INFINITY) ? 0.f : __expf(sv[t][r] - mx);
        sum += e[t];
      }
      #pragma unroll
      for (int off = 8; off; off >>= 1) sum += __shfl_xor(sum, off);
      const float rinv = (sum > 0.f) ? 1.f / sum : 0.f;
      #pragma unroll
      for (int t = 0; t < 5; ++t) p[t][r] = e[t] * rinv;
    }

    #pragma unroll
    for (int t = 0; t < 5; ++t)
      #pragma unroll
      for (int r = 0; r < 4; ++r)
        p_jm[grp][16 * t + c15][4 * g + r] = p[t][r];
  } else {
    // nontemporal zero fill for group grp's 16 rows (non-band f4s)
    #pragma unroll 1
    for (int rr = 0; rr < 16; ++rr) {
      const int m2 = grp * 16 + rr;
      const int i = i0 + m2;
      const int flo = (i >= 64) ? ((i - 64) >> 2) : 0;
      const int f1b = (i - 1) >> 2;
      float* arow = aout + (size_t)m2 * S;
      #pragma unroll 4
      for (int s = 0; s < 16; ++s) {
        const int f = s * 64 + lane;
        const bool band = (i >= 1) && (f >= flo) && (f <= f1b);
        if (!band) __builtin_nontemporal_store(z4, (fv4*)(arow + 4 * f));
      }
    }
  }
  __syncthreads();

  // ---- P3a: band writes — wave (grp,dh) owns rows grp*16 + dh*8 + [0,8) ----
  {
    const int mm = dh * 8 + g * 2 + (c15 >> 3);   // row within group
    const int m2 = grp * 16 + mm;
    const int i = i0 + m2;
    const int c8 = c15 & 7;
    if (i >= 1) {
      const int lo = (i >= 64) ? (i - 64) : 0;
      const int f0 = lo >> 2, f1 = (i - 1) >> 2;
      float* arow = aout + (size_t)m2 * S;
      #pragma unroll
      for (int pass = 0; pass < 3; ++pass) {
        const int f = f0 + c8 + (pass << 3);
        if (f <= f1) {
          fv4 v;
          #pragma unroll
          for (int c = 0; c < 4; ++c) {
            const int col = 4 * f + c;
            const bool in = (col >= lo) && (col < i);
            int rel = col - (i0g - 64);
            rel = rel < 0 ? 0 : rel;
            v[c] = in ? p_jm[grp][rel][mm] : 0.f;
          }
          __builtin_nontemporal_store(v, (fv4*)(arow + 4 * f));
        }
      }
    }
  }

  // ---- P3b: PV from LDS — wave (grp,dh): 16 queries, d-half dh ----
  f32x4 acc[16] = {};
  const int jstart = (i0g >= 64) ? 0 : (64 - i0g);
  const int cbase = (dh << 9) + (lane << 3);      // byte col: 4 u16 per lane
  #pragma unroll 2
  for (int j = jstart; j < 79; ++j) {
    const int rl = grp * 16 + j;
    const int cb = cbase ^ ((rl & 7) << 4);
    const uint2 xu = *(const uint2*)((const char*)xs + rl * 1024 + cb);
    const float x0 = bflo(xu.x), x1 = bfhi(xu.x);
    const float x2 = bflo(xu.y), x3 = bfhi(xu.y);
    alignas(16) float pall[16];
    *(float4*)&pall[0]  = *(const float4*)&p_jm[grp][j][0];
    *(float4*)&pall[4]  = *(const float4*)&p_jm[grp][j][4];
    *(float4*)&pall[8]  = *(const float4*)&p_jm[grp][j][8];
    *(float4*)&pall[12] = *(const float4*)&p_jm[grp][j][12];
    #pragma unroll
    for (int m = 0; m < 16; ++m) {
      const fv4 xv = {x0, x1, x2, x3};
      const fv4 pp = {pall[m], pall[m], pall[m], pall[m]};
      acc[m] += pp * xv;
    }
  }

  #pragma unroll 1
  for (int m = 0; m < 16; ++m) {
    float* rr = out + (size_t)(qgg + m) * D2 + (dh << 8) + lane * 4;
    const fv4 r = {acc[m][0], acc[m][1], acc[m][2], acc[m][3]};
    __builtin_nontemporal_store(r, (fv4*)rr);
  }
}

extern "C" void kernel_launch(void* const* d_in, const int* in_sizes, int n_in,
                              void* d_out, int out_size, void* d_ws, size_t ws_size,
                              hipStream_t stream) {
  const float* states = (const float*)d_in[0];
  const float* W_q    = (const float*)d_in[1];
  const float* W_k    = (const float*)d_in[2];
  float* out = (float*)d_out;

  char* ws = (char*)d_ws;
  u16* Xb  = (u16*)(ws);                 // 16 MB
  u16* Qp  = (u16*)(ws + 16777216);      // 16 MB
  u16* MbT = (u16*)(ws + 33554432);      // 0.5 MB

  cast_f32_bf16<<<8192, 256, 0, stream>>>(states, Xb, 2097152);
  m_gemm<<<256, 256, 0, stream>>>(W_q, W_k, MbT);
  q_gemm<<<dim3(128, 4), 256, 0, stream>>>(Xb, MbT, Qp);
  attn_kernel<<<256, 512, 0, stream>>>(Qp, Xb, out);
}